// Round 3
// baseline (105.232 us; speedup 1.0000x reference)
//
#include <hip/hip_runtime.h>
#include <hip/hip_bf16.h>

// QConv1d: x (8,64,16384) f32, w (64,64,9) f32, bias (64) f32
// out (8,64,16384) f32 = conv1d(x, w, pad=4) * 0.125 + bias
// Strategy: cast to bf16 (weights pre-scaled by 0.125 — exact, power of two),
// MFMA f32_16x16x32_bf16, fp32 accumulate. One block = one n, 256-wide L
// tile, all 64 O. 4 waves split L 4 ways (64 cols each) and each wave covers
// all 64 O (m=0..3) so every B-fragment feeds 4 MFMAs and is read by exactly
// one wave: per-block LDS reads = 288 KB (half of the 2x2 wave layout).
#define C_IN    64
#define L_IN    16384
#define O_OUT   64
#define KTAP    9
#define LTILE   256
#define ROWS    272      // LTILE + 16 halo rows (global l in [l0-8, l0+264))
#define RSTRIDE 72       // 64 + 8 pad (multiple of 8 -> 16B-aligned b128 rows)

typedef short          bf16x8 __attribute__((ext_vector_type(8)));   // MFMA A/B frag
typedef unsigned short u16x8  __attribute__((ext_vector_type(8)));
typedef float          f32x4  __attribute__((ext_vector_type(4)));   // MFMA C/D frag
typedef float          f32x8v __attribute__((ext_vector_type(8)));

static __device__ __forceinline__ unsigned short f2bf(float f) {
  __hip_bfloat16 h = __float2bfloat16(f);   // round-to-nearest
  return __builtin_bit_cast(unsigned short, h);
}

// ---------------------------------------------------------------------------
// Pre-kernel: w[o][c][t] fp32 (stride-9 taps) -> W2[t][o][c] bf16 (c contig),
// pre-scaled by 0.125 (exact: power-of-two only touches the exponent).
// ---------------------------------------------------------------------------
__global__ void w_rearrange(const float* __restrict__ w,
                            unsigned short* __restrict__ w2) {
    int i = blockIdx.x * 256 + threadIdx.x;       // i = t*4096 + o*64 + c
    if (i >= KTAP * O_OUT * C_IN) return;
    int t  = i >> 12;
    int oc = i & 4095;                            // o*64 + c
    w2[i] = f2bf(w[oc * KTAP + t] * 0.125f);
}

// ---------------------------------------------------------------------------
// Main kernel.
// ---------------------------------------------------------------------------
__global__ __launch_bounds__(256, 3) void qconv_kernel(
    const float* __restrict__ x,
    const unsigned short* __restrict__ w2,    // bf16 bits, pre-scaled
    const float* __restrict__ bias,
    float* __restrict__ out) {

  __shared__ __align__(16) unsigned short xs[ROWS][RSTRIDE];  // bf16 x tile, [l][c]

  const int tid = threadIdx.x;
  const int n   = blockIdx.x >> 6;
  const int l0  = (blockIdx.x & 63) << 8;      // tile base along L
  const float* xn = x + (size_t)n * C_IN * L_IN;

  // ---- Phase 1: stage x tile into LDS, fp32->bf16, transposed to [l][c] --
  // 272 8x8 transpose units; 8 consecutive threads cover 256 B contiguous
  // global per c-row, and write 16B-aligned b128 rows into LDS.
  for (int idx = tid; idx < ROWS; idx += 256) {
    const int cb = idx & 7;
    const int lb = idx >> 3;
    const int c0 = cb << 3;
    const int gl0 = l0 - 8 + (lb << 3);        // global l of first row (32B-aligned)
    unsigned short vb[8][8];                    // [i=c][j=l], bf16 bits
    if (gl0 >= 0 && gl0 + 8 <= L_IN) {
#pragma unroll
      for (int i = 0; i < 8; ++i) {
        f32x8v v = *reinterpret_cast<const f32x8v*>(xn + (size_t)(c0 + i) * L_IN + gl0);
#pragma unroll
        for (int j = 0; j < 8; ++j) vb[i][j] = f2bf(v[j]);
      }
    } else {
      // edge tiles only: element-wise zero-fill outside [0, L)
      for (int i = 0; i < 8; ++i)
        for (int j = 0; j < 8; ++j) {
          int gl = gl0 + j;
          vb[i][j] = (gl >= 0 && gl < L_IN)
                         ? f2bf(xn[(size_t)(c0 + i) * L_IN + gl])
                         : (unsigned short)0;
        }
    }
#pragma unroll
    for (int j = 0; j < 8; ++j) {
      u16x8 wv;
#pragma unroll
      for (int i = 0; i < 8; ++i) wv[i] = vb[i][j];
      *reinterpret_cast<u16x8*>(&xs[(lb << 3) + j][c0]) = wv;
    }
  }
  __syncthreads();

  // ---- Phase 2: MFMA main loop ------------------------------------------
  const int wave = tid >> 6;        // L quarter: cols [wave*64, wave*64+64)
  const int lane = tid & 63;
  const int col  = lane & 15;
  const int quad = lane >> 4;

  f32x4 acc[4][4];                  // [m: o-tile][lt: l-tile]
#pragma unroll
  for (int m = 0; m < 4; ++m)
#pragma unroll
    for (int lt = 0; lt < 4; ++lt) acc[m][lt] = (f32x4){0.f, 0.f, 0.f, 0.f};

  // LDS row for out-col l = l0 + wave*64 + lt*16 + col at tap t:
  //   r = (l + t - 4) - (l0 - 8) = wave*64 + lt*16 + col + t + 4
  const int rbase = (wave << 6) + col + 4;

  for (int t = 0; t < KTAP; ++t) {
    // A-frags: W2[t][o][c]; lane holds o = m*16+col, c = k*32 + quad*8 .. +7
    bf16x8 a[4][2];
#pragma unroll
    for (int m = 0; m < 4; ++m)
#pragma unroll
      for (int k = 0; k < 2; ++k)
        a[m][k] = *reinterpret_cast<const bf16x8*>(
            w2 + (t << 12) + (((m << 4) + col) << 6) + (k << 5) + (quad << 3));

#pragma unroll
    for (int k = 0; k < 2; ++k) {
#pragma unroll
      for (int lt = 0; lt < 4; ++lt) {
        const int r = rbase + t + (lt << 4);
        const bf16x8 b = *reinterpret_cast<const bf16x8*>(&xs[r][(k << 5) + (quad << 3)]);
#pragma unroll
        for (int m = 0; m < 4; ++m)
          acc[m][lt] = __builtin_amdgcn_mfma_f32_16x16x32_bf16(a[m][k], b, acc[m][lt], 0, 0, 0);
      }
    }
  }

  // ---- Phase 3: epilogue: + bias (scale folded into w), fp32 store ------
  // D layout: col = lane&15 -> l, row = quad*4 + reg -> o
#pragma unroll
  for (int m = 0; m < 4; ++m) {
    const int obase = (m << 4) + (quad << 2);
    float bv[4];
#pragma unroll
    for (int reg = 0; reg < 4; ++reg) bv[reg] = bias[obase + reg];
#pragma unroll
    for (int lt = 0; lt < 4; ++lt) {
      const int l = l0 + (wave << 6) + (lt << 4) + col;
#pragma unroll
      for (int reg = 0; reg < 4; ++reg) {
        const int o = obase + reg;
        out[((size_t)(n * O_OUT + o) << 14) + l] = acc[m][lt][reg] + bv[reg];
      }
    }
  }
}

extern "C" void kernel_launch(void* const* d_in, const int* in_sizes, int n_in,
                              void* d_out, int out_size, void* d_ws, size_t ws_size,
                              hipStream_t stream) {
  const float*    x    = (const float*)d_in[0];
  const float*    w    = (const float*)d_in[1];
  const float*    bias = (const float*)d_in[2];
  float*          out  = (float*)d_out;
  unsigned short* w2   = (unsigned short*)d_ws;   // 73728 B scratch (bf16 weights)

  // 1) rearrange + downcast + pre-scale weights into d_ws (runs every call)
  w_rearrange<<<(KTAP * O_OUT * C_IN + 255) / 256, 256, 0, stream>>>(w, w2);

  // 2) fused conv-as-GEMM: 8 n * 64 L-tiles = 512 blocks
  qconv_kernel<<<8 * (L_IN / LTILE), 256, 0, stream>>>(x, w2, bias, out);
}

// Round 5
// 97.877 us; speedup vs baseline: 1.0751x; 1.0751x over previous
//
#include <hip/hip_runtime.h>
#include <hip/hip_bf16.h>

// QConv1d: x (8,64,16384) f32, w (64,64,9) f32, bias (64) f32
// out (8,64,16384) f32 = conv1d(x, w, pad=4) * 0.125 + bias
// Strategy: cast to bf16 (weights pre-scaled by 0.125 — exact, power of two),
// MFMA f32_16x16x32_bf16, fp32 accumulate, fp32 out.
// Round-5: round-2 wave layout (measured best: 2 O-halves x 2 L-halves),
// pair-packed bf16 conversion in staging, add-only epilogue.
#define C_IN    64
#define L_IN    16384
#define O_OUT   64
#define KTAP    9
#define LTILE   256
#define ROWS    272      // LTILE + 16 halo rows (global l in [l0-8, l0+264))
#define RSTRIDE 72       // 64 + 8 pad (multiple of 8 -> 16B-aligned b128 rows)

typedef short          bf16x8 __attribute__((ext_vector_type(8)));   // MFMA A/B frag
typedef unsigned short u16x8  __attribute__((ext_vector_type(8)));
typedef unsigned int   u32x4  __attribute__((ext_vector_type(4)));
typedef float          f32x4  __attribute__((ext_vector_type(4)));   // MFMA C/D frag
typedef float          f32x8v __attribute__((ext_vector_type(8)));

static __device__ __forceinline__ unsigned short f2bf(float f) {
  __hip_bfloat16 h = __float2bfloat16(f);   // round-to-nearest
  return __builtin_bit_cast(unsigned short, h);
}

// pack two floats -> one u32 of two bf16 (lo in low 16 bits)
static __device__ __forceinline__ unsigned int pk2(float lo, float hi) {
  return (unsigned int)f2bf(lo) | ((unsigned int)f2bf(hi) << 16);
}

// ---------------------------------------------------------------------------
// Pre-kernel: w[o][c][t] fp32 (stride-9 taps) -> W2[t][o][c] bf16 (c contig),
// pre-scaled by 0.125 (exact: power-of-two only touches the exponent).
// ---------------------------------------------------------------------------
__global__ void w_rearrange(const float* __restrict__ w,
                            unsigned short* __restrict__ w2) {
    int i = blockIdx.x * 256 + threadIdx.x;       // i = t*4096 + o*64 + c
    if (i >= KTAP * O_OUT * C_IN) return;
    int t  = i >> 12;
    int oc = i & 4095;                            // o*64 + c
    w2[i] = f2bf(w[oc * KTAP + t] * 0.125f);
}

// ---------------------------------------------------------------------------
// Main kernel: one block = one n, one 256-wide L tile, all 64 outputs.
// 4 waves in a 2(O) x 2(L) grid; each wave owns 32 O x 128 L.
// ---------------------------------------------------------------------------
__global__ __launch_bounds__(256) void qconv_kernel(
    const float* __restrict__ x,
    const unsigned short* __restrict__ w2,    // bf16 bits, pre-scaled
    const float* __restrict__ bias,
    float* __restrict__ out) {

  __shared__ __align__(16) unsigned short xs[ROWS][RSTRIDE];  // bf16 x tile, [l][c]

  const int tid = threadIdx.x;
  const int n   = blockIdx.x >> 6;
  const int l0  = (blockIdx.x & 63) << 8;      // tile base along L
  const float* xn = x + (size_t)n * C_IN * L_IN;

  // ---- Phase 1: stage x tile into LDS, fp32->bf16, transposed to [l][c] --
  // 272 8x8 transpose units; pair-packed bf16 conversion along c so each LDS
  // row word is one pack op.
  for (int idx = tid; idx < ROWS; idx += 256) {
    const int cb = idx & 7;
    const int lb = idx >> 3;
    const int c0 = cb << 3;
    const int gl0 = l0 - 8 + (lb << 3);        // global l of first row (32B-aligned)
    if (gl0 >= 0 && gl0 + 8 <= L_IN) {
      f32x8v v[8];
#pragma unroll
      for (int i = 0; i < 8; ++i)
        v[i] = *reinterpret_cast<const f32x8v*>(xn + (size_t)(c0 + i) * L_IN + gl0);
#pragma unroll
      for (int j = 0; j < 8; ++j) {
        u32x4 wv;
#pragma unroll
        for (int p = 0; p < 4; ++p)
          wv[p] = pk2(v[2 * p][j], v[2 * p + 1][j]);
        *reinterpret_cast<u32x4*>(&xs[(lb << 3) + j][c0]) = wv;
      }
    } else {
      // edge tiles only: element-wise zero-fill outside [0, L)
      unsigned short vb[8][8];                  // [i=c][j=l]
      for (int i = 0; i < 8; ++i)
        for (int j = 0; j < 8; ++j) {
          int gl = gl0 + j;
          vb[i][j] = (gl >= 0 && gl < L_IN)
                         ? f2bf(xn[(size_t)(c0 + i) * L_IN + gl])
                         : (unsigned short)0;
        }
      for (int j = 0; j < 8; ++j) {
        u16x8 wv;
        for (int i = 0; i < 8; ++i) wv[i] = vb[i][j];
        *reinterpret_cast<u16x8*>(&xs[(lb << 3) + j][c0]) = wv;
      }
    }
  }
  __syncthreads();

  // ---- Phase 2: MFMA main loop ------------------------------------------
  const int wave = tid >> 6;
  const int lane = tid & 63;
  const int wr   = wave >> 1;       // O half: o in [32*wr, 32*wr+32)
  const int wc   = wave & 1;        // L half: l-offset wc*128
  const int col  = lane & 15;
  const int quad = lane >> 4;

  f32x4 acc[2][8];
#pragma unroll
  for (int m = 0; m < 2; ++m)
#pragma unroll
    for (int lt = 0; lt < 8; ++lt) acc[m][lt] = (f32x4){0.f, 0.f, 0.f, 0.f};

  // LDS row for out-col l = l0 + wc*128 + lt*16 + col at tap t:
  //   r = (l + t - 4) - (l0 - 8) = wc*128 + lt*16 + col + t + 4
  const int rbase = (wc << 7) + col + 4;

  for (int t = 0; t < KTAP; ++t) {
    // A-frags: W2[t][o][c]; lane holds o = o0+col, c = k*32 + quad*8 .. +7
    bf16x8 a[2][2];
#pragma unroll
    for (int m = 0; m < 2; ++m)
#pragma unroll
      for (int k = 0; k < 2; ++k)
        a[m][k] = *reinterpret_cast<const bf16x8*>(
            w2 + (t << 12) + (((wr << 5) + (m << 4) + col) << 6) + (k << 5) + (quad << 3));

#pragma unroll
    for (int k = 0; k < 2; ++k) {
#pragma unroll
      for (int lt = 0; lt < 8; ++lt) {
        const int r = rbase + t + (lt << 4);
        const bf16x8 b = *reinterpret_cast<const bf16x8*>(&xs[r][(k << 5) + (quad << 3)]);
        acc[0][lt] = __builtin_amdgcn_mfma_f32_16x16x32_bf16(a[0][k], b, acc[0][lt], 0, 0, 0);
        acc[1][lt] = __builtin_amdgcn_mfma_f32_16x16x32_bf16(a[1][k], b, acc[1][lt], 0, 0, 0);
      }
    }
  }

  // ---- Phase 3: epilogue: + bias (0.125 folded into w), fp32 store ------
  // D layout: col = lane&15 -> l, row = quad*4 + reg -> o
#pragma unroll
  for (int m = 0; m < 2; ++m) {
    const int obase = (wr << 5) + (m << 4) + (quad << 2);
    float bv[4];
#pragma unroll
    for (int reg = 0; reg < 4; ++reg) bv[reg] = bias[obase + reg];
#pragma unroll
    for (int lt = 0; lt < 8; ++lt) {
      const int l = l0 + (wc << 7) + (lt << 4) + col;
#pragma unroll
      for (int reg = 0; reg < 4; ++reg) {
        const int o = obase + reg;
        out[((size_t)(n * O_OUT + o) << 14) + l] = acc[m][lt][reg] + bv[reg];
      }
    }
  }
}

extern "C" void kernel_launch(void* const* d_in, const int* in_sizes, int n_in,
                              void* d_out, int out_size, void* d_ws, size_t ws_size,
                              hipStream_t stream) {
  const float*    x    = (const float*)d_in[0];
  const float*    w    = (const float*)d_in[1];
  const float*    bias = (const float*)d_in[2];
  float*          out  = (float*)d_out;
  unsigned short* w2   = (unsigned short*)d_ws;   // 73728 B scratch (bf16 weights)

  // 1) rearrange + downcast + pre-scale weights into d_ws (runs every call)
  w_rearrange<<<(KTAP * O_OUT * C_IN + 255) / 256, 256, 0, stream>>>(w, w2);

  // 2) fused conv-as-GEMM: 8 n * 64 L-tiles = 512 blocks
  qconv_kernel<<<8 * (L_IN / LTILE), 256, 0, stream>>>(x, w2, bias, out);
}